// Round 7
// baseline (489.446 us; speedup 1.0000x reference)
//
#include <hip/hip_runtime.h>

#define N_NODES 50000
#define N_EDGES 600000
#define DD 128
#define NBLK_FUSED 2048
#define NWAVES (NBLK_FUSED * 4)
#define RUN ((N_EDGES + NWAVES - 1) / NWAVES)   // 74 edges per wave

typedef __attribute__((ext_vector_type(8))) short short8;
typedef __attribute__((ext_vector_type(4))) float f32x4;

__device__ __forceinline__ short f2bf(float f) {
    union { float f; unsigned u; } v; v.f = f;
    unsigned r = v.u + 0x7fffu + ((v.u >> 16) & 1u);
    return (short)(r >> 16);
}
__device__ __forceinline__ float bf2f(short s) {
    union { float f; unsigned u; } v; v.u = ((unsigned)(unsigned short)s) << 16;
    return v.f;
}
__device__ __forceinline__ float u2f(unsigned u) {
    union { float f; unsigned u; } v; v.u = u;
    return v.f;
}

// ---------------------------------------------------------------------------
// Streaming GEMM: Y = X @ W^T + bias -> bf16. W staged frag-major in LDS
// (2048 fragments x 16B; barrier between write and read makes the
// short-store/short8-load mix safe).
// ---------------------------------------------------------------------------
__global__ __launch_bounds__(256) void k_lin(const float* __restrict__ X,
                                             const float* __restrict__ W,
                                             const float* __restrict__ bias,
                                             short* __restrict__ Y,
                                             int ntiles) {
    __shared__ __align__(16) short Wf[128 * 128];
    for (int i = threadIdx.x; i < 2048; i += 256) {
        const int fl = i & 63, fr = i >> 6;
        const int nt = fr >> 2, ks = fr & 3, fg = fl >> 4, fln = fl & 15;
        const float* s = W + (nt * 16 + fln) * DD + ks * 32 + fg * 8;
        short* d = Wf + i * 8;
#pragma unroll
        for (int j = 0; j < 8; ++j) d[j] = f2bf(s[j]);
    }
    __syncthreads();

    const int wave = threadIdx.x >> 6;
    const int lane = threadIdx.x & 63;
    const int g = lane >> 4, ln = lane & 15;

    float bb[8];
#pragma unroll
    for (int nt = 0; nt < 8; ++nt) bb[nt] = bias[nt * 16 + ln];

    for (int t = blockIdx.x * 4 + wave; t < ntiles; t += gridDim.x * 4) {
        const float* xr = X + (size_t)(t * 16 + ln) * DD;
        short8 a[4];
#pragma unroll
        for (int ks = 0; ks < 4; ++ks) {
            const float* p = xr + ks * 32 + g * 8;
            float4 t0 = *(const float4*)p;
            float4 t1 = *(const float4*)(p + 4);
            short8 v;
            v[0] = f2bf(t0.x); v[1] = f2bf(t0.y); v[2] = f2bf(t0.z); v[3] = f2bf(t0.w);
            v[4] = f2bf(t1.x); v[5] = f2bf(t1.y); v[6] = f2bf(t1.z); v[7] = f2bf(t1.w);
            a[ks] = v;
        }
#pragma unroll
        for (int nt = 0; nt < 8; ++nt) {
            f32x4 acc = {0.f, 0.f, 0.f, 0.f};
#pragma unroll
            for (int ks = 0; ks < 4; ++ks) {
                short8 b = *(const short8*)(Wf + (((nt << 2) + ks) * 64 + lane) * 8);
                acc = __builtin_amdgcn_mfma_f32_16x16x32_bf16(a[ks], b, acc, 0, 0, 0);
            }
#pragma unroll
            for (int r = 0; r < 4; ++r)
                Y[(size_t)(t * 16 + g * 4 + r) * DD + nt * 16 + ln] = f2bf(acc[r] + bb[nt]);
        }
    }
}

// ---------------------------------------------------------------------------
// CSR construction
// ---------------------------------------------------------------------------
__global__ __launch_bounds__(256) void k_zero_int(int* __restrict__ p, int n) {
    int i = blockIdx.x * 256 + threadIdx.x;
    if (i < n) p[i] = 0;
}

__global__ __launch_bounds__(256) void k_count(const int* __restrict__ EI,
                                               int* __restrict__ counts) {
    int e = blockIdx.x * 256 + threadIdx.x;
    if (e < N_EDGES) atomicAdd(&counts[EI[2 * e + 1]], 1);
}

__global__ __launch_bounds__(256) void k_scan1(const int* __restrict__ counts,
                                               int* __restrict__ scanned,
                                               int* __restrict__ bsum) {
    __shared__ int tmp[256];
    const int t = threadIdx.x;
    const int i = blockIdx.x * 256 + t;
    int v = (i < N_NODES) ? counts[i] : 0;
    tmp[t] = v;
    __syncthreads();
#pragma unroll
    for (int off = 1; off < 256; off <<= 1) {
        int x = (t >= off) ? tmp[t - off] : 0;
        __syncthreads();
        tmp[t] += x;
        __syncthreads();
    }
    if (i < N_NODES) scanned[i] = tmp[t] - v;
    if (t == 255) bsum[blockIdx.x] = tmp[255];
}

__global__ __launch_bounds__(256) void k_scan2(int* __restrict__ bsum, int nb) {
    __shared__ int tmp[256];
    const int t = threadIdx.x;
    int v = (t < nb) ? bsum[t] : 0;
    tmp[t] = v;
    __syncthreads();
#pragma unroll
    for (int off = 1; off < 256; off <<= 1) {
        int x = (t >= off) ? tmp[t - off] : 0;
        __syncthreads();
        tmp[t] += x;
        __syncthreads();
    }
    if (t < nb) bsum[t] = tmp[t] - v;
}

__global__ __launch_bounds__(256) void k_scan3(const int* __restrict__ scanned,
                                               const int* __restrict__ bsum,
                                               int* __restrict__ offsets,
                                               int* __restrict__ cursor) {
    int i = blockIdx.x * 256 + threadIdx.x;
    if (i < N_NODES) {
        int off = scanned[i] + bsum[blockIdx.x];
        offsets[i] = off;
        cursor[i] = off;
    }
    if (i == 0) offsets[N_NODES] = N_EDGES;
}

__global__ __launch_bounds__(256) void k_scatter(const int* __restrict__ EI,
                                                 int* __restrict__ cursor,
                                                 int2* __restrict__ sorted) {
    int e = blockIdx.x * 256 + threadIdx.x;
    if (e < N_EDGES) {
        int2 sd = *(const int2*)(EI + 2 * e);
        int pos = atomicAdd(&cursor[sd.y], 1);
        sorted[pos] = make_int2(e, sd.x);       // {edge id, src}
    }
}

// ---------------------------------------------------------------------------
// Fused rel-GEMM + aggregation over sorted edges, edge-balanced runs.
// Msg staging tile is unsigned-typed on BOTH write and read sides (same
// pointer) so the compiler sees the LDS dependence (no barrier needed
// within a wave once must-alias is visible).
// ---------------------------------------------------------------------------
__global__ __launch_bounds__(256) void k_fused(const float* __restrict__ RV,
                                               const int2* __restrict__ sorted,
                                               const int* __restrict__ offs,
                                               const float* __restrict__ W,
                                               const float* __restrict__ bias,
                                               const short* __restrict__ OL,
                                               float* __restrict__ out) {
    __shared__ __align__(16) short Wf[128 * 128];
    __shared__ __align__(16) unsigned stg[4][1160];   // [col][9] words, odd stride

    for (int i = threadIdx.x; i < 2048; i += 256) {
        const int fl = i & 63, fr = i >> 6;
        const int nt = fr >> 2, ks = fr & 3, fg = fl >> 4, fln = fl & 15;
        const float* s = W + (nt * 16 + fln) * DD + ks * 32 + fg * 8;
        short* d = Wf + i * 8;
#pragma unroll
        for (int j = 0; j < 8; ++j) d[j] = f2bf(s[j]);
    }
    __syncthreads();

    const int wave = threadIdx.x >> 6;
    const int lane = threadIdx.x & 63;
    const int g = lane >> 4, ln = lane & 15;
    unsigned* st = stg[wave];

    const int wid = blockIdx.x * 4 + wave;
    const int p0 = wid * RUN;
    if (p0 >= N_EDGES) return;
    const int p1 = min(p0 + RUN, N_EDGES);

    const float br0 = bias[lane];
    const float br1 = bias[lane + 64];
    const unsigned short* OLu = (const unsigned short*)OL;

    // binary search: largest d with offs[d] <= p0
    int d;
    {
        int lo = 0, hi = N_NODES - 1;
        while (lo < hi) {
            int mid = (lo + hi + 1) >> 1;
            if (offs[mid] <= p0) lo = mid; else hi = mid - 1;
        }
        d = lo;
    }
    int seg_hi = offs[d + 1];
    bool interior = (offs[d] >= p0) && (seg_hi <= p1);
    float od0 = bf2f((short)OLu[(size_t)d * DD + lane]);
    float od1 = bf2f((short)OLu[(size_t)d * DD + lane + 64]);
    float a0 = 0.f, a1 = 0.f;

    // prefetch chunk 0
    int2 mp_c;
    float4 ar_c[8];
    {
        const int idx = min(p0 + ln, N_EDGES - 1);
        mp_c = sorted[idx];
        const float* base = RV + (size_t)mp_c.x * DD;
#pragma unroll
        for (int ks = 0; ks < 4; ++ks) {
            ar_c[2 * ks]     = *(const float4*)(base + ks * 32 + g * 8);
            ar_c[2 * ks + 1] = *(const float4*)(base + ks * 32 + g * 8 + 4);
        }
    }

    for (int pos = p0; pos < p1; pos += 16) {
        // fire next chunk's loads early
        int2 mp_n;
        float4 ar_n[8];
        const bool have = (pos + 16) < p1;
        if (have) {
            const int idx = min(pos + 16 + ln, N_EDGES - 1);
            mp_n = sorted[idx];
            const float* base = RV + (size_t)mp_n.x * DD;
#pragma unroll
            for (int ks = 0; ks < 4; ++ks) {
                ar_n[2 * ks]     = *(const float4*)(base + ks * 32 + g * 8);
                ar_n[2 * ks + 1] = *(const float4*)(base + ks * 32 + g * 8 + 4);
            }
        }

        // convert + MFMA on current chunk
        short8 af[4];
#pragma unroll
        for (int ks = 0; ks < 4; ++ks) {
            float4 t0 = ar_c[2 * ks], t1 = ar_c[2 * ks + 1];
            short8 v;
            v[0] = f2bf(t0.x); v[1] = f2bf(t0.y); v[2] = f2bf(t0.z); v[3] = f2bf(t0.w);
            v[4] = f2bf(t1.x); v[5] = f2bf(t1.y); v[6] = f2bf(t1.z); v[7] = f2bf(t1.w);
            af[ks] = v;
        }
        f32x4 acc[8];
#pragma unroll
        for (int nt = 0; nt < 8; ++nt) {
            acc[nt] = (f32x4){0.f, 0.f, 0.f, 0.f};
#pragma unroll
            for (int ks = 0; ks < 4; ++ks) {
                short8 b = *(const short8*)(Wf + (((nt << 2) + ks) * 64 + lane) * 8);
                acc[nt] = __builtin_amdgcn_mfma_f32_16x16x32_bf16(af[ks], b, acc[nt], 0, 0, 0);
            }
        }

        // stage msg tile bf16-packed: word (e>>1) of col c; rows g*4+r
#pragma unroll
        for (int nt = 0; nt < 8; ++nt) {
            const unsigned lo = ((unsigned)(unsigned short)f2bf(acc[nt][0])) |
                                (((unsigned)(unsigned short)f2bf(acc[nt][1])) << 16);
            const unsigned hi = ((unsigned)(unsigned short)f2bf(acc[nt][2])) |
                                (((unsigned)(unsigned short)f2bf(acc[nt][3])) << 16);
            const int c = nt * 16 + ln;
            st[c * 9 + g * 2]     = lo;
            st[c * 9 + g * 2 + 1] = hi;
        }

        // per-edge epilogue (wave-uniform control flow)
        const int n = min(16, p1 - pos);
        for (int e = 0; e < n; ++e) {
            const int pe = pos + e;
            if (pe == seg_hi) {
                if (interior) {
                    out[(size_t)d * DD + lane]      = a0;
                    out[(size_t)d * DD + lane + 64] = a1;
                } else {
                    atomicAdd(&out[(size_t)d * DD + lane], a0);
                    atomicAdd(&out[(size_t)d * DD + lane + 64], a1);
                }
                a0 = a1 = 0.f;
                do { ++d; } while (offs[d + 1] <= pe);
                seg_hi = offs[d + 1];
                interior = (offs[d] >= p0) && (seg_hi <= p1);
                od0 = bf2f((short)OLu[(size_t)d * DD + lane]);
                od1 = bf2f((short)OLu[(size_t)d * DD + lane + 64]);
            }
            const int src = __shfl(mp_c.y, e);
            const unsigned w0 = st[lane * 9 + (e >> 1)];
            const unsigned w1 = st[(lane + 64) * 9 + (e >> 1)];
            const float s0 = (e & 1) ? u2f(w0 & 0xffff0000u) : u2f(w0 << 16);
            const float s1 = (e & 1) ? u2f(w1 & 0xffff0000u) : u2f(w1 << 16);
            const float m0 = s0 + br0 + bf2f((short)OLu[(size_t)src * DD + lane]) + od0;
            const float m1 = s1 + br1 + bf2f((short)OLu[(size_t)src * DD + lane + 64]) + od1;
            a0 += fmaxf(m0, 0.f);
            a1 += fmaxf(m1, 0.f);
        }

        if (have) {
            mp_c = mp_n;
#pragma unroll
            for (int q = 0; q < 8; ++q) ar_c[q] = ar_n[q];
        }
    }

    // final flush
    if (interior) {
        out[(size_t)d * DD + lane]      = a0;
        out[(size_t)d * DD + lane + 64] = a1;
    } else {
        atomicAdd(&out[(size_t)d * DD + lane], a0);
        atomicAdd(&out[(size_t)d * DD + lane + 64], a1);
    }
}

// ---------------------------------------------------------------------------
// Zero + final ReLU passes over out
// ---------------------------------------------------------------------------
__global__ __launch_bounds__(256) void k_zerof(float4* __restrict__ p, int n4) {
    int i = blockIdx.x * 256 + threadIdx.x;
    if (i < n4) p[i] = (float4){0.f, 0.f, 0.f, 0.f};
}

__global__ __launch_bounds__(256) void k_relu(float4* __restrict__ p, int n4) {
    int i = blockIdx.x * 256 + threadIdx.x;
    if (i < n4) {
        float4 v = p[i];
        v.x = fmaxf(v.x, 0.f); v.y = fmaxf(v.y, 0.f);
        v.z = fmaxf(v.z, 0.f); v.w = fmaxf(v.w, 0.f);
        p[i] = v;
    }
}

// ---------------------------------------------------------------------------
extern "C" void kernel_launch(void* const* d_in, const int* in_sizes, int n_in,
                              void* d_out, int out_size, void* d_ws, size_t ws_size,
                              hipStream_t stream) {
    const float* obj = (const float*)d_in[0];
    const float* rel = (const float*)d_in[1];
    const int*   ei  = (const int*)d_in[2];
    const float* Wo  = (const float*)d_in[3];
    const float* bo  = (const float*)d_in[4];
    const float* Wr  = (const float*)d_in[5];
    const float* br  = (const float*)d_in[6];
    float* out = (float*)d_out;

    char* ws = (char*)d_ws;
    short* OLb     = (short*)ws;                     // 12,800,000 B
    int2*  sorted  = (int2*)(ws + 12800000);         //  4,800,000 B
    int*   counts  = (int*)(ws + 17600000);
    int*   scanned = (int*)(ws + 17800192);
    int*   offsets = (int*)(ws + 18000896);          // 50001 ints
    int*   cursor  = (int*)(ws + 18201600);
    int*   bsum    = (int*)(ws + 18401792);

    const int NB_E = (N_EDGES + 255) / 256;          // 2344
    const int NB_N = (N_NODES + 255) / 256;          // 196
    const int n4 = N_NODES * DD / 4;                 // 1,600,000

    k_zero_int<<<NB_N, 256, 0, stream>>>(counts, N_NODES);
    k_count<<<NB_E, 256, 0, stream>>>(ei, counts);
    k_scan1<<<NB_N, 256, 0, stream>>>(counts, scanned, bsum);
    k_scan2<<<1, 256, 0, stream>>>(bsum, NB_N);
    k_scan3<<<NB_N, 256, 0, stream>>>(scanned, bsum, offsets, cursor);
    k_scatter<<<NB_E, 256, 0, stream>>>(ei, cursor, sorted);
    k_lin<<<782, 256, 0, stream>>>(obj, Wo, bo, OLb, N_NODES / 16);
    k_zerof<<<(n4 + 255) / 256, 256, 0, stream>>>((float4*)out, n4);
    k_fused<<<NBLK_FUSED, 256, 0, stream>>>(rel, sorted, offsets, Wr, br, OLb, out);
    k_relu<<<(n4 + 255) / 256, 256, 0, stream>>>((float4*)out, n4);
}

// Round 8
// 258.673 us; speedup vs baseline: 1.8921x; 1.8921x over previous
//
#include <hip/hip_runtime.h>

#define N_NODES 50000
#define N_EDGES 600000
#define DD 128

typedef __attribute__((ext_vector_type(8))) short short8;
typedef __attribute__((ext_vector_type(4))) float f32x4;

__device__ __forceinline__ short f2bf(float f) {
    union { float f; unsigned u; } v; v.f = f;
    unsigned r = v.u + 0x7fffu + ((v.u >> 16) & 1u);
    return (short)(r >> 16);
}
__device__ __forceinline__ float bf2f(short s) {
    union { float f; unsigned u; } v; v.u = ((unsigned)(unsigned short)s) << 16;
    return v.f;
}
__device__ __forceinline__ float u2f(unsigned u) {
    union { float f; unsigned u; } v; v.u = u;
    return v.f;
}

// ---------------------------------------------------------------------------
// Streaming GEMM: Y = X @ W^T + bias -> bf16 (obj_lin). W frag-major in LDS.
// ---------------------------------------------------------------------------
__global__ __launch_bounds__(256) void k_lin(const float* __restrict__ X,
                                             const float* __restrict__ W,
                                             const float* __restrict__ bias,
                                             short* __restrict__ Y,
                                             int ntiles) {
    __shared__ __align__(16) short Wf[128 * 128];
    for (int i = threadIdx.x; i < 2048; i += 256) {
        const int fl = i & 63, fr = i >> 6;
        const int nt = fr >> 2, ks = fr & 3, fg = fl >> 4, fln = fl & 15;
        const float* s = W + (nt * 16 + fln) * DD + ks * 32 + fg * 8;
        short* d = Wf + i * 8;
#pragma unroll
        for (int j = 0; j < 8; ++j) d[j] = f2bf(s[j]);
    }
    __syncthreads();

    const int wave = threadIdx.x >> 6;
    const int lane = threadIdx.x & 63;
    const int g = lane >> 4, ln = lane & 15;

    float bb[8];
#pragma unroll
    for (int nt = 0; nt < 8; ++nt) bb[nt] = bias[nt * 16 + ln];

    for (int t = blockIdx.x * 4 + wave; t < ntiles; t += gridDim.x * 4) {
        const float* xr = X + (size_t)(t * 16 + ln) * DD;
        short8 a[4];
#pragma unroll
        for (int ks = 0; ks < 4; ++ks) {
            const float* p = xr + ks * 32 + g * 8;
            float4 t0 = *(const float4*)p;
            float4 t1 = *(const float4*)(p + 4);
            short8 v;
            v[0] = f2bf(t0.x); v[1] = f2bf(t0.y); v[2] = f2bf(t0.z); v[3] = f2bf(t0.w);
            v[4] = f2bf(t1.x); v[5] = f2bf(t1.y); v[6] = f2bf(t1.z); v[7] = f2bf(t1.w);
            a[ks] = v;
        }
#pragma unroll
        for (int nt = 0; nt < 8; ++nt) {
            f32x4 acc = {0.f, 0.f, 0.f, 0.f};
#pragma unroll
            for (int ks = 0; ks < 4; ++ks) {
                short8 b = *(const short8*)(Wf + (((nt << 2) + ks) * 64 + lane) * 8);
                acc = __builtin_amdgcn_mfma_f32_16x16x32_bf16(a[ks], b, acc, 0, 0, 0);
            }
#pragma unroll
            for (int r = 0; r < 4; ++r)
                Y[(size_t)(t * 16 + g * 4 + r) * DD + nt * 16 + ln] = f2bf(acc[r] + bb[nt]);
        }
    }
}

// ---------------------------------------------------------------------------
// CSR-rank construction: counts -> scan -> perm[e] = dst-sorted position
// ---------------------------------------------------------------------------
__global__ __launch_bounds__(256) void k_zero_int(int* __restrict__ p, int n) {
    int i = blockIdx.x * 256 + threadIdx.x;
    if (i < n) p[i] = 0;
}

__global__ __launch_bounds__(256) void k_count(const int* __restrict__ EI,
                                               int* __restrict__ counts) {
    int e = blockIdx.x * 256 + threadIdx.x;
    if (e < N_EDGES) atomicAdd(&counts[EI[2 * e + 1]], 1);
}

__global__ __launch_bounds__(256) void k_scan1(const int* __restrict__ counts,
                                               int* __restrict__ scanned,
                                               int* __restrict__ bsum) {
    __shared__ int tmp[256];
    const int t = threadIdx.x;
    const int i = blockIdx.x * 256 + t;
    int v = (i < N_NODES) ? counts[i] : 0;
    tmp[t] = v;
    __syncthreads();
#pragma unroll
    for (int off = 1; off < 256; off <<= 1) {
        int x = (t >= off) ? tmp[t - off] : 0;
        __syncthreads();
        tmp[t] += x;
        __syncthreads();
    }
    if (i < N_NODES) scanned[i] = tmp[t] - v;
    if (t == 255) bsum[blockIdx.x] = tmp[255];
}

__global__ __launch_bounds__(256) void k_scan2(int* __restrict__ bsum, int nb) {
    __shared__ int tmp[256];
    const int t = threadIdx.x;
    int v = (t < nb) ? bsum[t] : 0;
    tmp[t] = v;
    __syncthreads();
#pragma unroll
    for (int off = 1; off < 256; off <<= 1) {
        int x = (t >= off) ? tmp[t - off] : 0;
        __syncthreads();
        tmp[t] += x;
        __syncthreads();
    }
    if (t < nb) bsum[t] = tmp[t] - v;
}

__global__ __launch_bounds__(256) void k_scan3(const int* __restrict__ scanned,
                                               const int* __restrict__ bsum,
                                               int* __restrict__ offsets,
                                               int* __restrict__ cursor) {
    int i = blockIdx.x * 256 + threadIdx.x;
    if (i < N_NODES) {
        int off = scanned[i] + bsum[blockIdx.x];
        offsets[i] = off;
        cursor[i] = off;
    }
    if (i == 0) offsets[N_NODES] = N_EDGES;
}

__global__ __launch_bounds__(256) void k_scatter2(const int* __restrict__ EI,
                                                  int* __restrict__ cursor,
                                                  int* __restrict__ perm) {
    int e = blockIdx.x * 256 + threadIdx.x;
    if (e < N_EDGES)
        perm[e] = atomicAdd(&cursor[EI[2 * e + 1]], 1);
}

// ---------------------------------------------------------------------------
// Fused rel-GEMM + OL[src] add + scatter-write to dst-sorted position.
// Streaming reads (rel, EI, perm), random L3 reads (OL[src], 128B-coalesced),
// fire-and-forget 256B scatter writes (Ys). No segment logic, no atomics.
// ---------------------------------------------------------------------------
__global__ __launch_bounds__(256) void k_fl(const float* __restrict__ RV,
                                            const int* __restrict__ EI,
                                            const int* __restrict__ perm,
                                            const float* __restrict__ W,
                                            const float* __restrict__ bias,
                                            const short* __restrict__ OL,
                                            unsigned short* __restrict__ Ys) {
    __shared__ __align__(16) short Wf[128 * 128];
    __shared__ __align__(16) unsigned stg[4][1160];   // [col][9] words, odd stride

    for (int i = threadIdx.x; i < 2048; i += 256) {
        const int fl = i & 63, fr = i >> 6;
        const int nt = fr >> 2, ks = fr & 3, fg = fl >> 4, fln = fl & 15;
        const float* s = W + (nt * 16 + fln) * DD + ks * 32 + fg * 8;
        short* d = Wf + i * 8;
#pragma unroll
        for (int j = 0; j < 8; ++j) d[j] = f2bf(s[j]);
    }
    __syncthreads();

    const int wave = threadIdx.x >> 6;
    const int lane = threadIdx.x & 63;
    const int g = lane >> 4, ln = lane & 15;
    unsigned* st = stg[wave];

    const float br0 = bias[lane];
    const float br1 = bias[lane + 64];
    const unsigned short* OLu = (const unsigned short*)OL;
    const int NT = N_EDGES / 16;                      // 37500 exact

    for (int t = blockIdx.x * 4 + wave; t < NT; t += gridDim.x * 4) {
        const int e0 = t * 16;

        // A-fragment: row ln <- rel_vecs[e0+ln] (sequential streaming)
        const float* xr = RV + (size_t)(e0 + ln) * DD;
        short8 a[4];
#pragma unroll
        for (int ks = 0; ks < 4; ++ks) {
            const float* p = xr + ks * 32 + g * 8;
            float4 t0 = *(const float4*)p;
            float4 t1 = *(const float4*)(p + 4);
            short8 v;
            v[0] = f2bf(t0.x); v[1] = f2bf(t0.y); v[2] = f2bf(t0.z); v[3] = f2bf(t0.w);
            v[4] = f2bf(t1.x); v[5] = f2bf(t1.y); v[6] = f2bf(t1.z); v[7] = f2bf(t1.w);
            a[ks] = v;
        }

        // src + sorted position for the 16 edges (lanes 0..15 load, shfl later)
        int sp = 0, pp = 0;
        if (lane < 16) {
            sp = EI[2 * (e0 + lane)];
            pp = perm[e0 + lane];
        }

        f32x4 acc[8];
#pragma unroll
        for (int nt = 0; nt < 8; ++nt) {
            acc[nt] = (f32x4){0.f, 0.f, 0.f, 0.f};
#pragma unroll
            for (int ks = 0; ks < 4; ++ks) {
                short8 b = *(const short8*)(Wf + (((nt << 2) + ks) * 64 + lane) * 8);
                acc[nt] = __builtin_amdgcn_mfma_f32_16x16x32_bf16(a[ks], b, acc[nt], 0, 0, 0);
            }
        }

        // stage msg tile bf16-packed: word (e>>1) of col c; rows g*4+r
#pragma unroll
        for (int nt = 0; nt < 8; ++nt) {
            const unsigned lo = ((unsigned)(unsigned short)f2bf(acc[nt][0])) |
                                (((unsigned)(unsigned short)f2bf(acc[nt][1])) << 16);
            const unsigned hi = ((unsigned)(unsigned short)f2bf(acc[nt][2])) |
                                (((unsigned)(unsigned short)f2bf(acc[nt][3])) << 16);
            const int c = nt * 16 + ln;
            st[c * 9 + g * 2]     = lo;
            st[c * 9 + g * 2 + 1] = hi;
        }

        // epilogue: 16 independent iterations (pipelinable): add OL[src]+b_rel,
        // write row to Ys[pos] (two 128B halves per edge)
#pragma unroll 4
        for (int e = 0; e < 16; ++e) {
            const int src = __shfl(sp, e);
            const int pos = __shfl(pp, e);
            const unsigned w0 = st[lane * 9 + (e >> 1)];
            const unsigned w1 = st[(lane + 64) * 9 + (e >> 1)];
            const float s0 = (e & 1) ? u2f(w0 & 0xffff0000u) : u2f(w0 << 16);
            const float s1 = (e & 1) ? u2f(w1 & 0xffff0000u) : u2f(w1 << 16);
            const float y0 = s0 + br0 + bf2f((short)OLu[(size_t)src * DD + lane]);
            const float y1 = s1 + br1 + bf2f((short)OLu[(size_t)src * DD + lane + 64]);
            Ys[(size_t)pos * DD + lane]      = (unsigned short)f2bf(y0);
            Ys[(size_t)pos * DD + lane + 64] = (unsigned short)f2bf(y1);
        }
    }
}

// ---------------------------------------------------------------------------
// Segment sum: one wave per node, fully sequential y-rows, relu inside+out.
// Writes every node (deg-0 -> 0), so no zero/relu passes needed.
// ---------------------------------------------------------------------------
__global__ __launch_bounds__(256) void k_segsum(const unsigned short* __restrict__ Ys,
                                                const short* __restrict__ OL,
                                                const int* __restrict__ offs,
                                                float* __restrict__ out) {
    const int wave = threadIdx.x >> 6;
    const int lane = threadIdx.x & 63;
    const int v = blockIdx.x * 4 + wave;
    if (v >= N_NODES) return;

    const int r0 = offs[v], r1 = offs[v + 1];
    const unsigned short* OLu = (const unsigned short*)OL;
    const float od0 = bf2f((short)OLu[(size_t)v * DD + lane]);
    const float od1 = bf2f((short)OLu[(size_t)v * DD + lane + 64]);

    float a0 = 0.f, a1 = 0.f;
    int r = r0;
    for (; r + 2 <= r1; r += 2) {
        const float y00 = bf2f((short)Ys[(size_t)r * DD + lane]);
        const float y01 = bf2f((short)Ys[(size_t)r * DD + lane + 64]);
        const float y10 = bf2f((short)Ys[(size_t)(r + 1) * DD + lane]);
        const float y11 = bf2f((short)Ys[(size_t)(r + 1) * DD + lane + 64]);
        a0 += fmaxf(y00 + od0, 0.f) + fmaxf(y10 + od0, 0.f);
        a1 += fmaxf(y01 + od1, 0.f) + fmaxf(y11 + od1, 0.f);
    }
    if (r < r1) {
        a0 += fmaxf(bf2f((short)Ys[(size_t)r * DD + lane]) + od0, 0.f);
        a1 += fmaxf(bf2f((short)Ys[(size_t)r * DD + lane + 64]) + od1, 0.f);
    }

    out[(size_t)v * DD + lane]      = fmaxf(a0, 0.f);
    out[(size_t)v * DD + lane + 64] = fmaxf(a1, 0.f);
}

// ---------------------------------------------------------------------------
extern "C" void kernel_launch(void* const* d_in, const int* in_sizes, int n_in,
                              void* d_out, int out_size, void* d_ws, size_t ws_size,
                              hipStream_t stream) {
    const float* obj = (const float*)d_in[0];
    const float* rel = (const float*)d_in[1];
    const int*   ei  = (const int*)d_in[2];
    const float* Wo  = (const float*)d_in[3];
    const float* bo  = (const float*)d_in[4];
    const float* Wr  = (const float*)d_in[5];
    const float* br  = (const float*)d_in[6];
    float* out = (float*)d_out;

    char* ws = (char*)d_ws;
    unsigned short* Ys = (unsigned short*)ws;        // 153,600,000 B
    short* OLb     = (short*)(ws + 153600000);       //  12,800,000 B
    int*   perm    = (int*)(ws + 166400000);         //   2,400,000 B
    int*   counts  = (int*)(ws + 168800000);         //     200,000 B
    int*   scanned = (int*)(ws + 169000192);         //     200,704 B
    int*   offsets = (int*)(ws + 169200896);         //     200,704 B (50001 ints)
    int*   cursor  = (int*)(ws + 169401600);         //     200,000 B
    int*   bsum    = (int*)(ws + 169601792);         //       1,024 B

    const int NB_E = (N_EDGES + 255) / 256;          // 2344
    const int NB_N = (N_NODES + 255) / 256;          // 196

    k_zero_int<<<NB_N, 256, 0, stream>>>(counts, N_NODES);
    k_count<<<NB_E, 256, 0, stream>>>(ei, counts);
    k_scan1<<<NB_N, 256, 0, stream>>>(counts, scanned, bsum);
    k_scan2<<<1, 256, 0, stream>>>(bsum, NB_N);
    k_scan3<<<NB_N, 256, 0, stream>>>(scanned, bsum, offsets, cursor);
    k_scatter2<<<NB_E, 256, 0, stream>>>(ei, cursor, perm);
    k_lin<<<782, 256, 0, stream>>>(obj, Wo, bo, OLb, N_NODES / 16);
    k_fl<<<2048, 256, 0, stream>>>(rel, ei, perm, Wr, br, OLb, Ys);
    k_segsum<<<(N_NODES + 3) / 4, 256, 0, stream>>>(Ys, OLb, offsets, out);
}